// Round 1
// 680.187 us; speedup vs baseline: 1.0032x; 1.0032x over previous
//
#include <hip/hip_runtime.h>

// Problem constants (match reference).
#define NROWS 1048576
#define NC    128
#define EPSF  1e-12f

// ---------------------------------------------------------------------------
// R2 insight: the reference F1 only ever reads 5 slices of the confusion
// matrix:
//   TP_c  = conf[c,c]          -> diag[c]
//   FP_c  = 127*conf[c,1] + conf[c,0]   -> col1[c], col0[c]
//   FN_c  = 127*conf[1,c] + conf[0,c]   -> row1[c], row0[c]
// So we never materialize the 128x128 matrix. We keep 5 x 128 int counters.
// For uniform-random (t, pred) only ~5/128 of rows touch ANY counter, so the
// hot loop has no global atomics at all (the R1 version's in-loop global
// atomicAdd sat on the vmcnt critical path: next iteration's loads could not
// be consumed until the contended cross-XCD atomic retired -> ~330us instead
// of the ~85us HBM floor). Counters live in 2.5 KB of LDS per block (LDS
// atomics, lgkm pipe, rare) and are flushed once per block (~20 nonzero
// global atomics/block, ~40K total).
//
// Workspace counter layout: 5 arrays of NC ints.
#define DIAG  0
#define COL0  (NC)
#define COL1  (2 * NC)
#define ROW0  (3 * NC)
#define ROW1  (4 * NC)
#define NCOUNT (5 * NC)

// ---------------------------------------------------------------------------
// Kernel 1: quarter-wave-per-row argmax + sparse counter update.
// Lane q of a 16-lane quarter loads float4 at cols [4q..4q+3] and
// [64+4q..64+4q+3] -> 256 B contiguous per quarter per load, all bytes used.
// Local 8-element argmax scanned in increasing column order with strict '>'
// (jnp.argmax first-occurrence tie-break), then 4 butterfly steps (masks
// 1,2,4,8 stay inside the 16-lane group).
// ---------------------------------------------------------------------------
__global__ void __launch_bounds__(256) argmax_conf_kernel(
    const float* __restrict__ y_pred,
    const int*   __restrict__ y_true,
    int*         __restrict__ counts,
    int n_rows)
{
    __shared__ int lcnt[NCOUNT];

    for (int i = threadIdx.x; i < NCOUNT; i += blockDim.x) lcnt[i] = 0;
    __syncthreads();

    const int tid     = blockIdx.x * blockDim.x + threadIdx.x;
    const int lane    = threadIdx.x & 63;
    const int q       = lane & 15;        // lane within quarter
    const int quarter = (lane >> 4);      // which of 4 rows this wave iter
    const int wave    = tid >> 6;
    const int nwaves  = (gridDim.x * blockDim.x) >> 6;

    for (int base = wave * 4; base < n_rows; base += nwaves * 4) {
        const int row = base + quarter;

        float v   = -3.4e38f;
        int   idx = 0;

        // Hoist the y_true load so its latency overlaps the argmax compute.
        const int t = (q == 0 && row < n_rows) ? y_true[row] : 0;

        if (row < n_rows) {
            const float4* rowp = (const float4*)(y_pred + (size_t)row * NC);
            const float4 a = rowp[q];        // cols 4q .. 4q+3
            const float4 b = rowp[q + 16];   // cols 64+4q .. 64+4q+3

            // In-order scan, strict > : lowest column wins ties.
            v = a.x; idx = 4 * q;
            if (a.y > v) { v = a.y; idx = 4 * q + 1; }
            if (a.z > v) { v = a.z; idx = 4 * q + 2; }
            if (a.w > v) { v = a.w; idx = 4 * q + 3; }
            if (b.x > v) { v = b.x; idx = 64 + 4 * q; }
            if (b.y > v) { v = b.y; idx = 64 + 4 * q + 1; }
            if (b.z > v) { v = b.z; idx = 64 + 4 * q + 2; }
            if (b.w > v) { v = b.w; idx = 64 + 4 * q + 3; }
        }

        // Butterfly within the 16-lane quarter (masks < 16 never cross it).
        #pragma unroll
        for (int off = 1; off < 16; off <<= 1) {
            float ov = __shfl_xor(v, off, 64);
            int   oi = __shfl_xor(idx, off, 64);
            if (ov > v || (ov == v && oi < idx)) { v = ov; idx = oi; }
        }

        if (q == 0 && row < n_rows) {
            // Each condition fires with prob ~1/128 on this data -> these
            // LDS atomics are rare and off the vmem critical path.
            if (idx == t) atomicAdd(&lcnt[DIAG + t], 1);
            if (idx == 0) atomicAdd(&lcnt[COL0 + t], 1);
            if (idx == 1) atomicAdd(&lcnt[COL1 + t], 1);
            if (t == 0)   atomicAdd(&lcnt[ROW0 + idx], 1);
            if (t == 1)   atomicAdd(&lcnt[ROW1 + idx], 1);
        }
    }

    __syncthreads();

    // Per-block flush: only nonzero slots (~20/block on this data).
    for (int i = threadIdx.x; i < NCOUNT; i += blockDim.x) {
        const int c = lcnt[i];
        if (c) atomicAdd(&counts[i], c);
    }
}

// ---------------------------------------------------------------------------
// Kernel 2: per-class F1 + mean, single 128-thread block, from the 5 slices.
// ---------------------------------------------------------------------------
__global__ void f1_mean_kernel(const int* __restrict__ counts,
                               float* __restrict__ out)
{
    __shared__ float partial[NC];
    const int c = threadIdx.x;

    const float TP = (float)counts[DIAG + c];
    const float FP = (float)(NC - 1) * (float)counts[COL1 + c] + (float)counts[COL0 + c];
    const float FN = (float)(NC - 1) * (float)counts[ROW1 + c] + (float)counts[ROW0 + c];

    const float sens = TP / (TP + FN + EPSF);
    const float prec = TP / (TP + FP + EPSF);
    const float f1   = 2.0f * (prec * sens / (prec + sens + EPSF));

    partial[c] = f1;
    __syncthreads();

    #pragma unroll
    for (int s = 64; s > 0; s >>= 1) {
        if (c < s) partial[c] += partial[c + s];
        __syncthreads();
    }

    if (c == 0) out[0] = partial[0] / (float)NC;
}

extern "C" void kernel_launch(void* const* d_in, const int* in_sizes, int n_in,
                              void* d_out, int out_size, void* d_ws, size_t ws_size,
                              hipStream_t stream)
{
    const float* y_pred = (const float*)d_in[0];
    const int*   y_true = (const int*)d_in[1];
    float*       out    = (float*)d_out;
    int*         counts = (int*)d_ws;   // 5*128*4 = 2560 B of scratch

    const int n_rows = in_sizes[1];     // N = 1048576

    // d_ws is poisoned to 0xAA before every timed call — zero the counters.
    hipMemsetAsync(counts, 0, NCOUNT * sizeof(int), stream);

    // 2048 blocks x 256 thr = 8192 waves x 4 rows/iter -> 32 iters/wave.
    // 8 blocks/CU x 4 waves = full 32-wave/CU occupancy (VGPR use is tiny).
    argmax_conf_kernel<<<2048, 256, 0, stream>>>(y_pred, y_true, counts, n_rows);

    f1_mean_kernel<<<1, NC, 0, stream>>>(counts, out);
}